// Round 9
// baseline (367.936 us; speedup 1.0000x reference)
//
#include <hip/hip_runtime.h>
#include <stdint.h>

#define KNN 16
#define LROWS 8
#define KBQ 8     // queries per knn block
#define KCAP 128  // survivor cap per query (E[survivors]~17, rank-stat)

// ---------------------------------------------------------------------------
// Load 4 consecutive points (AoS, dense). Same fmaf d2 expression everywhere
// -> bitwise-consistent between passes.
// ---------------------------------------------------------------------------
__device__ __forceinline__ void load4(const float* __restrict__ sxyz, int i0,
                                      int N, float px[4], float py[4],
                                      float pz[4]) {
  if (i0 + 4 <= N) {
    float4 v0 = *(const float4*)&sxyz[3 * i0];
    float4 v1 = *(const float4*)&sxyz[3 * i0 + 4];
    float4 v2 = *(const float4*)&sxyz[3 * i0 + 8];
    px[0] = v0.x; py[0] = v0.y; pz[0] = v0.z;
    px[1] = v0.w; py[1] = v1.x; pz[1] = v1.y;
    px[2] = v1.z; py[2] = v1.w; pz[2] = v2.x;
    px[3] = v2.y; py[3] = v2.z; pz[3] = v2.w;
  } else {
#pragma unroll
    for (int e = 0; e < 4; ++e) {
      int i = i0 + e; bool ok = i < N;
      px[e] = ok ? sxyz[3 * i] : 0.f;
      py[e] = ok ? sxyz[3 * i + 1] : 0.f;
      pz[e] = ok ? sxyz[3 * i + 2] : 0.f;
    }
  }
}

// ---------------------------------------------------------------------------
// KNN: point-parallel, query-broadcast. 256 threads, 8 queries per block.
// R9: wave-uniform FAST PATH — iterations fully inside [max qlo, min qhi)
// skip per-element range checks + select (11 -> 7 VALU ops/elem-query).
// Same fmaf d2 expression + same fminf/threshold semantics in both paths ->
// bitwise-identical results. Boundary iterations take the original path.
// ---------------------------------------------------------------------------
__global__ __launch_bounds__(256) void knn_kernel(
    const float* __restrict__ sxyz, const int* __restrict__ bidx,
    const int* __restrict__ fidx, int* __restrict__ col, int N, int Q) {
  const int t = threadIdx.x;
  const int qbase = blockIdx.x * KBQ;

  __shared__ float s_min[KBQ][256];
  __shared__ unsigned long long s_cand[KBQ][KCAP];
  __shared__ int s_cnt[KBQ];
  __shared__ float s_thr[KBQ];
  __shared__ float s_qx[KBQ], s_qy[KBQ], s_qz[KBQ];
  __shared__ int s_lo[KBQ], s_hi[KBQ];

  // meta: t<8 -> xyz + lower bound, t in [8,16) -> upper bound
  if (t < 2 * KBQ) {
    int qi = qbase + (t & (KBQ - 1));
    if (qi < Q) {
      int fi = fidx[qi];
      int qb = bidx[fi];
      if (t < KBQ) {
        s_qx[t] = sxyz[3 * fi]; s_qy[t] = sxyz[3 * fi + 1]; s_qz[t] = sxyz[3 * fi + 2];
        int a = 0, b = N;
        while (a < b) { int m = (a + b) >> 1; if (bidx[m] < qb) a = m + 1; else b = m; }
        s_lo[t] = a;
      } else {
        int a = 0, b = N;
        while (a < b) { int m = (a + b) >> 1; if (bidx[m] <= qb) a = m + 1; else b = m; }
        s_hi[t - KBQ] = a;
      }
    } else {
      if (t < KBQ) { s_lo[t] = 0; s_qx[t] = s_qy[t] = s_qz[t] = 0.f; }
      else s_hi[t - KBQ] = 0;
    }
  }
  if (t < KBQ) s_cnt[t] = 0;
  __syncthreads();

  float qx[KBQ], qy[KBQ], qz[KBQ], qmin[KBQ];
  int qlo[KBQ], qhi[KBQ];
#pragma unroll
  for (int qi = 0; qi < KBQ; ++qi) {
    qx[qi] = s_qx[qi]; qy[qi] = s_qy[qi]; qz[qi] = s_qz[qi];
    qlo[qi] = s_lo[qi]; qhi[qi] = s_hi[qi];
    qmin[qi] = 3e38f;
  }
  int blo = qlo[0], bhi = qhi[0];
  int fp_lo = qlo[0], fp_hi = qhi[0];
#pragma unroll
  for (int qi = 1; qi < KBQ; ++qi) {
    blo = min(blo, qlo[qi]); bhi = max(bhi, qhi[qi]);
    fp_lo = max(fp_lo, qlo[qi]); fp_hi = min(fp_hi, qhi[qi]);
  }
  const int base = blo & ~3;

  // --- pass 1: per-thread minima per query ---
  for (int i0 = base + 4 * t; i0 < bhi; i0 += 1024) {
    float px[4], py[4], pz[4];
    load4(sxyz, i0, N, px, py, pz);
    if (i0 >= fp_lo && i0 + 4 <= fp_hi) {
      // fast path: all 4 points valid for all 8 queries
#pragma unroll
      for (int e = 0; e < 4; ++e) {
#pragma unroll
        for (int qi = 0; qi < KBQ; ++qi) {
          float dx = qx[qi] - px[e], dy = qy[qi] - py[e], dz = qz[qi] - pz[e];
          float d2 = fmaf(dx, dx, fmaf(dy, dy, dz * dz));
          qmin[qi] = fminf(qmin[qi], d2);
        }
      }
    } else {
#pragma unroll
      for (int e = 0; e < 4; ++e) {
        int i = i0 + e;
#pragma unroll
        for (int qi = 0; qi < KBQ; ++qi) {
          float dx = qx[qi] - px[e], dy = qy[qi] - py[e], dz = qz[qi] - pz[e];
          float d2 = fmaf(dx, dx, fmaf(dy, dy, dz * dz));
          bool v = (i >= qlo[qi]) && (i < qhi[qi]);
          qmin[qi] = fminf(qmin[qi], v ? d2 : 3e38f);
        }
      }
    }
  }
#pragma unroll
  for (int qi = 0; qi < KBQ; ++qi) s_min[qi][t] = qmin[qi];
  __syncthreads();

  // --- threshold: 16th smallest of 256 minima; 32-thread group per query ---
  {
    int qi = t >> 5, u = t & 31;
    float v[8];
#pragma unroll
    for (int s = 0; s < 8; ++s) v[s] = s_min[qi][u + 32 * s];
    float thr = 3e38f;
    for (int r = 0; r < KNN; ++r) {
      float lm = fminf(fminf(fminf(v[0], v[1]), fminf(v[2], v[3])),
                       fminf(fminf(v[4], v[5]), fminf(v[6], v[7])));
      float gm = lm;
      gm = fminf(gm, __shfl_xor(gm, 1, 64));
      gm = fminf(gm, __shfl_xor(gm, 2, 64));
      gm = fminf(gm, __shfl_xor(gm, 4, 64));
      gm = fminf(gm, __shfl_xor(gm, 8, 64));
      gm = fminf(gm, __shfl_xor(gm, 16, 64));
      unsigned long long b = __ballot(lm == gm);
      unsigned mask = (unsigned)((b >> (t & 32)) & 0xffffffffull);
      int win = __ffs(mask) - 1;
      if (u == win) {  // knock exactly one instance
        if (v[0] == gm) v[0] = 3e38f; else if (v[1] == gm) v[1] = 3e38f;
        else if (v[2] == gm) v[2] = 3e38f; else if (v[3] == gm) v[3] = 3e38f;
        else if (v[4] == gm) v[4] = 3e38f; else if (v[5] == gm) v[5] = 3e38f;
        else if (v[6] == gm) v[6] = 3e38f; else v[7] = 3e38f;
      }
      thr = gm;
    }
    if (u == 0)
      s_thr[qi] = (s_hi[qi] - s_lo[qi] <= KCAP) ? 3e38f : thr;  // tiny-segment exact
  }
  __syncthreads();

  float qthr[KBQ];
#pragma unroll
  for (int qi = 0; qi < KBQ; ++qi) qthr[qi] = s_thr[qi];

  // --- pass 2: collect survivors ---
  for (int i0 = base + 4 * t; i0 < bhi; i0 += 1024) {
    float px[4], py[4], pz[4];
    load4(sxyz, i0, N, px, py, pz);
    if (i0 >= fp_lo && i0 + 4 <= fp_hi) {
      // fast path: validity guaranteed; same d2 expr + threshold compare
#pragma unroll
      for (int e = 0; e < 4; ++e) {
        int i = i0 + e;
#pragma unroll
        for (int qi = 0; qi < KBQ; ++qi) {
          float dx = qx[qi] - px[e], dy = qy[qi] - py[e], dz = qz[qi] - pz[e];
          float d2 = fmaf(dx, dx, fmaf(dy, dy, dz * dz));
          if (d2 <= qthr[qi]) {
            int pos = atomicAdd(&s_cnt[qi], 1);
            if (pos < KCAP)
              s_cand[qi][pos] =
                  (((unsigned long long)__float_as_uint(d2)) << 32) | (unsigned)i;
          }
        }
      }
    } else {
#pragma unroll
      for (int e = 0; e < 4; ++e) {
        int i = i0 + e;
#pragma unroll
        for (int qi = 0; qi < KBQ; ++qi) {
          float dx = qx[qi] - px[e], dy = qy[qi] - py[e], dz = qz[qi] - pz[e];
          float d2 = fmaf(dx, dx, fmaf(dy, dy, dz * dz));
          if (i >= qlo[qi] && i < qhi[qi] && d2 <= qthr[qi]) {
            int pos = atomicAdd(&s_cnt[qi], 1);
            if (pos < KCAP)
              s_cand[qi][pos] =
                  (((unsigned long long)__float_as_uint(d2)) << 32) | (unsigned)i;
          }
        }
      }
    }
  }
  __syncthreads();

  // --- extraction: 32-thread group per query, 16 exact min rounds ---
  {
    int qi = t >> 5, u = t & 31;
    int M = min(s_cnt[qi], KCAP);
    for (int r = 0; r < KNN; ++r) {
      unsigned long long lm = ~0ull; int ls = -1;
      for (int s = u; s < M; s += 32) {
        unsigned long long vv = s_cand[qi][s];
        if (vv < lm) { lm = vv; ls = s; }
      }
      unsigned long long gm = lm, o;
      o = __shfl_xor(gm, 1, 64); if (o < gm) gm = o;
      o = __shfl_xor(gm, 2, 64); if (o < gm) gm = o;
      o = __shfl_xor(gm, 4, 64); if (o < gm) gm = o;
      o = __shfl_xor(gm, 8, 64); if (o < gm) gm = o;
      o = __shfl_xor(gm, 16, 64); if (o < gm) gm = o;
      unsigned long long b = __ballot(lm == gm);
      unsigned mask = (unsigned)((b >> (t & 32)) & 0xffffffffull);
      int win = __ffs(mask) - 1;
      if (u == win && ls >= 0 && gm != ~0ull) {
        s_cand[qi][ls] = ~0ull;  // group is intra-wave -> in-order LDS, no barrier
        col[(size_t)(qbase + qi) * KNN + r] = (int)(unsigned)(gm & 0xffffffffull);
      }
    }
  }
}

// ---------------------------------------------------------------------------
// Fused per-query kernel — r7 body verbatim (best measured: 153.6us).
// r8 lesson: inlining the auction cost +17us in fused but saved only ~8 in
// the remainder -> split structure is better; reverted.
// ---------------------------------------------------------------------------
#define OFF_LEAF 0     // 8 rows x stride 388 (pad 4/row, 16B rows)
#define OFF_EDGE 3104  // 16 x 132 (16B-aligned rows)
#define OFF_B 5216     // union: hidden 16x68 | cls 16x132
#define OFF_EW 7328    // 16 x 12 ; reused as mat 8x17 in EXT=false
#define OFF_FC 7520    // 16 x 20
#define S_TOTAL 7840

template <bool EXT>
__global__ __launch_bounds__(128) void fused_kernel(
    const float* __restrict__ sxyz,
    const int* __restrict__ fidx,
    const float* __restrict__ gcn,
    const float* __restrict__ leaf,
    const float* __restrict__ W1, const float* __restrict__ b1,
    const float* __restrict__ W2, const float* __restrict__ b2,
    const float* __restrict__ Wl, const float* __restrict__ bl,
    const int* __restrict__ col,
    float* __restrict__ matw, float* __restrict__ out) {
  const int q = blockIdx.x;
  const int t = threadIdx.x;
  const int lane = t & 63;
  const int kbase = (t >> 6) * 8;  // wave 0 -> k 0..7, wave 1 -> k 8..15

  __shared__ __align__(16) float S[S_TOTAL];
  __shared__ int s_col[KNN];
  __shared__ float s_rna[24];
  __shared__ float s_rnb[3][KNN];

  // --- stage leaf (12 KB) first: coalesced float4, latency hidden by MLP ---
  {
    const float4* lp = (const float4*)(leaf + (size_t)q * 3072);
#pragma unroll
    for (int r = 0; r < 6; ++r) {
      int v = r * 128 + t;
      float4 f = lp[v];
      int l = v / 96, off = (v % 96) * 4;
      *(float4*)&S[OFF_LEAF + l * 388 + off] = f;
    }
  }
  if (t < KNN) s_col[t] = col[q * KNN + t];
  __syncthreads();

  for (int v = t; v < KNN * 20; v += 128)
    S[OFF_FC + v] = gcn[(size_t)s_col[v / 20] * 148 + 128 + (v % 20)];
  if (t < KNN) {
    int fi = fidx[q];
    float qx = sxyz[3 * fi], qy = sxyz[3 * fi + 1], qz = sxyz[3 * fi + 2];
    int j = s_col[t];
    float jx = sxyz[3 * j], jy = sxyz[3 * j + 1], jz = sxyz[3 * j + 2];
    float dx = qx - jx, dy = qy - jy, dz = qz - jz;
    float dist = sqrtf(dx * dx + dy * dy + dz * dz);
    float* e = &S[OFF_EW + t * 12];
    e[0] = qx; e[1] = qy; e[2] = qz;
    e[3] = jx; e[4] = jy; e[5] = jz;
    e[6] = dx; e[7] = dy; e[8] = dz; e[9] = dist;
  }
  __syncthreads();

  // MLP layer 1 -> hidden (region B, stride 68). EW row as 3x b128 broadcast;
  // components used in ascending i order -> exact.
  for (int r = 0; r < 8; ++r) {
    int o = r * 128 + t;
    int k = o >> 6, jj = o & 63;
    const float* e = &S[OFF_EW + k * 12];
    float4 e0 = *(const float4*)&e[0];
    float4 e1 = *(const float4*)&e[4];
    float4 e2 = *(const float4*)&e[8];
    float acc0 = b1[jj];
    acc0 = fmaf(e0.x, W1[0 * 64 + jj], acc0);
    acc0 = fmaf(e0.y, W1[1 * 64 + jj], acc0);
    acc0 = fmaf(e0.z, W1[2 * 64 + jj], acc0);
    acc0 = fmaf(e0.w, W1[3 * 64 + jj], acc0);
    acc0 = fmaf(e1.x, W1[4 * 64 + jj], acc0);
    acc0 = fmaf(e1.y, W1[5 * 64 + jj], acc0);
    acc0 = fmaf(e1.z, W1[6 * 64 + jj], acc0);
    acc0 = fmaf(e1.w, W1[7 * 64 + jj], acc0);
    acc0 = fmaf(e2.x, W1[8 * 64 + jj], acc0);
    acc0 = fmaf(e2.y, W1[9 * 64 + jj], acc0);
    S[OFF_B + k * 68 + jj] = fmaxf(acc0, 0.0f);
  }
  __syncthreads();

  // MLP layer 2, k-split across waves: wave w -> k=8w..8w+7, h0=lane,
  // h1=lane+64. W2 dword loads coalesced; chain b2[h] + j ascending -> exact.
  {
    float accA[8], accB[8];
#pragma unroll
    for (int k = 0; k < 8; ++k) { accA[k] = b2[lane]; accB[k] = b2[lane + 64]; }
#pragma unroll
    for (int j4 = 0; j4 < 16; ++j4) {
      float4 hv[8];
#pragma unroll
      for (int k = 0; k < 8; ++k)
        hv[k] = *(const float4*)&S[OFF_B + (kbase + k) * 68 + 4 * j4];
#pragma unroll
      for (int jj = 0; jj < 4; ++jj) {
        float wA = W2[(4 * j4 + jj) * 128 + lane];
        float wB = W2[(4 * j4 + jj) * 128 + lane + 64];
#pragma unroll
        for (int k = 0; k < 8; ++k) {
          float hvj = (jj == 0) ? hv[k].x : (jj == 1) ? hv[k].y
                    : (jj == 2) ? hv[k].z : hv[k].w;
          accA[k] = fmaf(hvj, wA, accA[k]);
          accB[k] = fmaf(hvj, wB, accB[k]);
        }
      }
    }
#pragma unroll
    for (int k = 0; k < 8; ++k) {
      S[OFF_EDGE + (kbase + k) * 132 + lane] = accA[k];
      S[OFF_EDGE + (kbase + k) * 132 + lane + 64] = accB[k];
    }
  }
  __syncthreads();  // hidden fully consumed before cls overwrites region B

  // cls GEMV -> region B (stride 132), k-split like MLP2. Wl in 2x20 regs;
  // fc rows as 5x b128 broadcast. Chain: bl[h] + c ascending -> exact.
  {
    float wlA[20], wlB[20];
#pragma unroll
    for (int c = 0; c < 20; ++c) {
      wlA[c] = Wl[c * 128 + lane];
      wlB[c] = Wl[c * 128 + lane + 64];
    }
#pragma unroll
    for (int k = 0; k < 8; ++k) {
      const float* fc = &S[OFF_FC + (kbase + k) * 20];
      float4 f0 = *(const float4*)&fc[0];
      float4 f1 = *(const float4*)&fc[4];
      float4 f2 = *(const float4*)&fc[8];
      float4 f3 = *(const float4*)&fc[12];
      float4 f4 = *(const float4*)&fc[16];
      float aA = bl[lane], aB = bl[lane + 64];
      aA = fmaf(f0.x, wlA[0], aA);  aB = fmaf(f0.x, wlB[0], aB);
      aA = fmaf(f0.y, wlA[1], aA);  aB = fmaf(f0.y, wlB[1], aB);
      aA = fmaf(f0.z, wlA[2], aA);  aB = fmaf(f0.z, wlB[2], aB);
      aA = fmaf(f0.w, wlA[3], aA);  aB = fmaf(f0.w, wlB[3], aB);
      aA = fmaf(f1.x, wlA[4], aA);  aB = fmaf(f1.x, wlB[4], aB);
      aA = fmaf(f1.y, wlA[5], aA);  aB = fmaf(f1.y, wlB[5], aB);
      aA = fmaf(f1.z, wlA[6], aA);  aB = fmaf(f1.z, wlB[6], aB);
      aA = fmaf(f1.w, wlA[7], aA);  aB = fmaf(f1.w, wlB[7], aB);
      aA = fmaf(f2.x, wlA[8], aA);  aB = fmaf(f2.x, wlB[8], aB);
      aA = fmaf(f2.y, wlA[9], aA);  aB = fmaf(f2.y, wlB[9], aB);
      aA = fmaf(f2.z, wlA[10], aA); aB = fmaf(f2.z, wlB[10], aB);
      aA = fmaf(f2.w, wlA[11], aA); aB = fmaf(f2.w, wlB[11], aB);
      aA = fmaf(f3.x, wlA[12], aA); aB = fmaf(f3.x, wlB[12], aB);
      aA = fmaf(f3.y, wlA[13], aA); aB = fmaf(f3.y, wlB[13], aB);
      aA = fmaf(f3.z, wlA[14], aA); aB = fmaf(f3.z, wlB[14], aB);
      aA = fmaf(f3.w, wlA[15], aA); aB = fmaf(f3.w, wlB[15], aB);
      aA = fmaf(f4.x, wlA[16], aA); aB = fmaf(f4.x, wlB[16], aB);
      aA = fmaf(f4.y, wlA[17], aA); aB = fmaf(f4.y, wlB[17], aB);
      aA = fmaf(f4.z, wlA[18], aA); aB = fmaf(f4.z, wlB[18], aB);
      aA = fmaf(f4.w, wlA[19], aA); aB = fmaf(f4.w, wlB[19], aB);
      S[OFF_B + (kbase + k) * 132 + lane] = aA;
      S[OFF_B + (kbase + k) * 132 + lane + 64] = aB;
    }
  }
  __syncthreads();

  // 72 norm jobs. LDS reads as float4 (same component->accumulator mapping).
  if (t < 72) {
    float s0 = 0, s1 = 0, s2 = 0, s3 = 0;
    const float4* p;
    if (t < 24) p = (const float4*)&S[OFF_LEAF + (t / 3) * 388 + (t % 3) * 128];
    else if (t < 40) p = (const float4*)&S[OFF_EDGE + (t - 24) * 132];
    else if (t < 56) p = (const float4*)&S[OFF_B + (t - 40) * 132];
    else p = (const float4*)(gcn + (size_t)s_col[t - 56] * 148);
#pragma unroll 4
    for (int h = 0; h < 32; ++h) {
      float4 v = p[h];
      s0 = fmaf(v.x, v.x, s0); s1 = fmaf(v.y, v.y, s1);
      s2 = fmaf(v.z, v.z, s2); s3 = fmaf(v.w, v.w, s3);
    }
    float rn = 1.0f / fmaxf(sqrtf((s0 + s1) + (s2 + s3)), 1e-8f);
    if (t < 24) s_rna[t] = rn;
    else if (t < 40) s_rnb[0][t - 24] = rn;
    else if (t < 56) s_rnb[1][t - 40] = rn;
    else s_rnb[2][t - 56] = rn;
  }
  __syncthreads();

  // 128 cosine dots -> mat. fma component order unchanged -> exact.
  {
    int l = t >> 4, k = t & 15;
    const float* a0 = &S[OFF_LEAF + l * 388];
    const float* be = &S[OFF_EDGE + k * 132];
    const float* bc = &S[OFF_B + k * 132];
    const float* bf = gcn + (size_t)s_col[k] * 148;
    float d0 = 0, d1 = 0, d2 = 0;
    for (int h = 0; h < 128; h += 4) {
      float4 va0 = *(const float4*)&a0[h];
      float4 va1 = *(const float4*)&a0[128 + h];
      float4 va2 = *(const float4*)&a0[256 + h];
      float4 vbf = *(const float4*)&bf[h];
      float4 ve = *(const float4*)&be[h];
      float4 vc = *(const float4*)&bc[h];
      d0 = fmaf(va0.x, ve.x, d0); d0 = fmaf(va0.y, ve.y, d0);
      d0 = fmaf(va0.z, ve.z, d0); d0 = fmaf(va0.w, ve.w, d0);
      d1 = fmaf(va1.x, vc.x, d1); d1 = fmaf(va1.y, vc.y, d1);
      d1 = fmaf(va1.z, vc.z, d1); d1 = fmaf(va1.w, vc.w, d1);
      d2 = fmaf(va2.x, vbf.x, d2); d2 = fmaf(va2.y, vbf.y, d2);
      d2 = fmaf(va2.z, vbf.z, d2); d2 = fmaf(va2.w, vbf.w, d2);
    }
    float m = (d0 * s_rna[l * 3 + 0] * s_rnb[0][k] +
               d1 * s_rna[l * 3 + 1] * s_rnb[1][k]) * 0.25f +
              d2 * s_rna[l * 3 + 2] * s_rnb[2][k] * 0.5f;
    if (EXT) {
      matw[(size_t)q * 128 + t] = m;
      return;
    }
    S[OFF_EW + l * 17 + k] = m;  // mat 8x17 aliases dead EW region
  }
  __syncthreads();
  if (t >= 64) return;

  // fallback inline auction (workspace too small for mat)
  const float* s_mat = &S[OFF_EW];
  float mrow[KNN];
#pragma unroll
  for (int c = 0; c < KNN; ++c) mrow[c] = s_mat[(t & 7) * 17 + c];
  int ass = -1;
  float cost = 0.f;
  for (int it = 0; it < 1024; ++it) {
    float v1 = -3e38f, v2 = -3e38f; int c1 = 0;
#pragma unroll
    for (int c = 0; c < KNN; ++c) {
      float costc = __shfl(cost, c, 64);
      float v = mrow[c] - costc;
      if (v > v1) { v2 = v1; v1 = v; c1 = c; }
      else if (v > v2) v2 = v;
    }
    int bidc = (t < 8 && ass < 0) ? c1 : -1;
    float bidv = v1 - v2 + 0.125f;
    float high = -3e38f; int hb = -1;
#pragma unroll
    for (int r = 0; r < 8; ++r) {
      int bc = __shfl(bidc, r, 64);
      float bv = __shfl(bidv, r, 64);
      if (bc == t && bv > high) { high = bv; hb = r; }
    }
    if (t < 16 && hb >= 0) cost += high;
    int hb_c = __shfl(hb, bidc < 0 ? 0 : bidc, 64);
    int hb_a = __shfl(hb, ass < 0 ? 0 : ass, 64);
    if (t < 8) {
      if (ass >= 0 && hb_a >= 0) ass = -1;
      if (bidc >= 0 && hb_c == t) ass = bidc;
    }
    if (__ballot((t < 8) ? (ass >= 0) : 1) == ~0ull) break;
  }
  float s = 0.f;
#pragma unroll
  for (int r = 0; r < 8; ++r) {
    int a = __shfl(ass, r, 64);
    if (t == 0) s += s_mat[r * 17 + a];
  }
  if (t == 0) out[q] = s * 0.125f;
}

// ---------------------------------------------------------------------------
// Auction kernel: 16 lanes per query (rows=lanes 0..7, cols=lanes 0..15),
// 4 queries/wave, 16/block. Pure register+shuffle synchronous Jacobi with
// exact reference tie-breaks (strict > scans: lowest col / lowest row).
// ---------------------------------------------------------------------------
__global__ __launch_bounds__(256) void auction_kernel(
    const float* __restrict__ matw, float* __restrict__ out, int Q) {
  const int t = threadIdx.x;
  const int lane = t & 63;
  const int gj = lane & 15;
  const int gb = lane & ~15;  // group base within wave
  const int q = blockIdx.x * 16 + (t >> 6) * 4 + (lane >> 4);
  const bool valid = q < Q;

  float mrow[KNN];
  if (valid && gj < 8) {
    const float4* mp = (const float4*)(matw + (size_t)q * 128 + gj * 16);
    float4 a = mp[0], b = mp[1], c = mp[2], d = mp[3];
    mrow[0] = a.x; mrow[1] = a.y; mrow[2] = a.z; mrow[3] = a.w;
    mrow[4] = b.x; mrow[5] = b.y; mrow[6] = b.z; mrow[7] = b.w;
    mrow[8] = c.x; mrow[9] = c.y; mrow[10] = c.z; mrow[11] = c.w;
    mrow[12] = d.x; mrow[13] = d.y; mrow[14] = d.z; mrow[15] = d.w;
  } else {
#pragma unroll
    for (int c = 0; c < KNN; ++c) mrow[c] = 0.f;
  }
  int ass = (valid && gj < 8) ? -1 : 0;  // cols/invalid lanes report "done"
  float cost = 0.f;

  for (int it = 0; it < 512; ++it) {
    float v1 = -3e38f, v2 = -3e38f; int c1 = 0;
#pragma unroll
    for (int c = 0; c < KNN; ++c) {
      float costc = __shfl(cost, gb + c, 64);
      float v = mrow[c] - costc;
      if (v > v1) { v2 = v1; v1 = v; c1 = c; }
      else if (v > v2) v2 = v;
    }
    int bidc = (valid && gj < 8 && ass < 0) ? c1 : -1;
    float bidv = v1 - v2 + 0.125f;  // eps = 1/L

    float high = -3e38f; int hb = -1;
#pragma unroll
    for (int r = 0; r < 8; ++r) {
      int bc = __shfl(bidc, gb + r, 64);
      float bv = __shfl(bidv, gb + r, 64);
      if (bc == gj && bv > high) { high = bv; hb = r; }
    }
    if (hb >= 0) cost += high;  // lane gj == column gj

    int hb_c = __shfl(hb, gb + (bidc < 0 ? 0 : bidc), 64);
    int hb_a = __shfl(hb, gb + (ass < 0 ? 0 : ass), 64);
    if (valid && gj < 8) {
      if (ass >= 0 && hb_a >= 0) ass = -1;     // kicked
      if (bidc >= 0 && hb_c == gj) ass = bidc; // won
    }
    if (__ballot(ass >= 0) == ~0ull) break;
  }

  float val = 0.f;
  if (valid && gj < 8) {
#pragma unroll
    for (int c = 0; c < KNN; ++c) val = (ass == c) ? mrow[c] : val;
  }
  val += __shfl_xor(val, 1, 64);
  val += __shfl_xor(val, 2, 64);
  val += __shfl_xor(val, 4, 64);
  if (valid && gj == 0) out[q] = val * 0.125f;
}

// ---------------------------------------------------------------------------
extern "C" void kernel_launch(void* const* d_in, const int* in_sizes, int n_in,
                              void* d_out, int out_size, void* d_ws, size_t ws_size,
                              hipStream_t stream) {
  const float* sxyz = (const float*)d_in[0];
  const int* bidx = (const int*)d_in[1];
  const int* fidx = (const int*)d_in[2];
  const float* gcn = (const float*)d_in[3];
  const float* leaf = (const float*)d_in[4];
  const float* W1 = (const float*)d_in[5];
  const float* b1 = (const float*)d_in[6];
  const float* W2 = (const float*)d_in[7];
  const float* b2 = (const float*)d_in[8];
  const float* Wl = (const float*)d_in[9];
  const float* bl = (const float*)d_in[10];
  float* out = (float*)d_out;

  const int N = in_sizes[0] / 3;
  const int Q = in_sizes[2];

  char* ws = (char*)d_ws;
  int* col = (int*)ws;
  float* matw = (float*)(ws + (size_t)Q * KNN * 4);
  const size_t need = (size_t)Q * KNN * 4 + (size_t)Q * 128 * 4;

  knn_kernel<<<(Q + KBQ - 1) / KBQ, 256, 0, stream>>>(sxyz, bidx, fidx, col, N, Q);
  if (ws_size >= need) {
    fused_kernel<true><<<Q, 128, 0, stream>>>(sxyz, fidx, gcn, leaf, W1, b1, W2,
                                              b2, Wl, bl, col, matw, out);
    auction_kernel<<<(Q + 15) / 16, 256, 0, stream>>>(matw, out, Q);
  } else {
    fused_kernel<false><<<Q, 128, 0, stream>>>(sxyz, fidx, gcn, leaf, W1, b1, W2,
                                               b2, Wl, bl, col, nullptr, out);
  }
}

// Round 10
// 357.768 us; speedup vs baseline: 1.0284x; 1.0284x over previous
//
#include <hip/hip_runtime.h>
#include <stdint.h>

#define KNN 16
#define LROWS 8
#define KBQ 8     // queries per knn block
#define KCAP 128  // survivor cap per query (E[survivors]~17, rank-stat)

// ---------------------------------------------------------------------------
// Load 4 consecutive points (AoS, dense). Same fmaf d2 expression everywhere
// -> bitwise-consistent between passes.
// ---------------------------------------------------------------------------
__device__ __forceinline__ void load4(const float* __restrict__ sxyz, int i0,
                                      int N, float px[4], float py[4],
                                      float pz[4]) {
  if (i0 + 4 <= N) {
    float4 v0 = *(const float4*)&sxyz[3 * i0];
    float4 v1 = *(const float4*)&sxyz[3 * i0 + 4];
    float4 v2 = *(const float4*)&sxyz[3 * i0 + 8];
    px[0] = v0.x; py[0] = v0.y; pz[0] = v0.z;
    px[1] = v0.w; py[1] = v1.x; pz[1] = v1.y;
    px[2] = v1.z; py[2] = v1.w; pz[2] = v2.x;
    px[3] = v2.y; py[3] = v2.z; pz[3] = v2.w;
  } else {
#pragma unroll
    for (int e = 0; e < 4; ++e) {
      int i = i0 + e; bool ok = i < N;
      px[e] = ok ? sxyz[3 * i] : 0.f;
      py[e] = ok ? sxyz[3 * i + 1] : 0.f;
      pz[e] = ok ? sxyz[3 * i + 2] : 0.f;
    }
  }
}

// ---------------------------------------------------------------------------
// KNN: point-parallel, query-broadcast. 256 threads, 8 queries per block.
// Threshold per query = 16th smallest of the 256 per-thread minima (provable
// upper bound on true 16th-NN d2). Pass 2 collects survivors; exact top-16 by
// packed (d2,idx) key == lax.top_k tie semantics.
// R10 note: r9's wave-uniform fast path REGRESSED knn ~10us (doubled loop
// body broke the schedule) — reverted to this single-path form (r7 = best).
// ---------------------------------------------------------------------------
__global__ __launch_bounds__(256) void knn_kernel(
    const float* __restrict__ sxyz, const int* __restrict__ bidx,
    const int* __restrict__ fidx, int* __restrict__ col, int N, int Q) {
  const int t = threadIdx.x;
  const int qbase = blockIdx.x * KBQ;

  __shared__ float s_min[KBQ][256];
  __shared__ unsigned long long s_cand[KBQ][KCAP];
  __shared__ int s_cnt[KBQ];
  __shared__ float s_thr[KBQ];
  __shared__ float s_qx[KBQ], s_qy[KBQ], s_qz[KBQ];
  __shared__ int s_lo[KBQ], s_hi[KBQ];

  // meta: t<8 -> xyz + lower bound, t in [8,16) -> upper bound
  if (t < 2 * KBQ) {
    int qi = qbase + (t & (KBQ - 1));
    if (qi < Q) {
      int fi = fidx[qi];
      int qb = bidx[fi];
      if (t < KBQ) {
        s_qx[t] = sxyz[3 * fi]; s_qy[t] = sxyz[3 * fi + 1]; s_qz[t] = sxyz[3 * fi + 2];
        int a = 0, b = N;
        while (a < b) { int m = (a + b) >> 1; if (bidx[m] < qb) a = m + 1; else b = m; }
        s_lo[t] = a;
      } else {
        int a = 0, b = N;
        while (a < b) { int m = (a + b) >> 1; if (bidx[m] <= qb) a = m + 1; else b = m; }
        s_hi[t - KBQ] = a;
      }
    } else {
      if (t < KBQ) { s_lo[t] = 0; s_qx[t] = s_qy[t] = s_qz[t] = 0.f; }
      else s_hi[t - KBQ] = 0;
    }
  }
  if (t < KBQ) s_cnt[t] = 0;
  __syncthreads();

  float qx[KBQ], qy[KBQ], qz[KBQ], qmin[KBQ];
  int qlo[KBQ], qhi[KBQ];
#pragma unroll
  for (int qi = 0; qi < KBQ; ++qi) {
    qx[qi] = s_qx[qi]; qy[qi] = s_qy[qi]; qz[qi] = s_qz[qi];
    qlo[qi] = s_lo[qi]; qhi[qi] = s_hi[qi];
    qmin[qi] = 3e38f;
  }
  int blo = qlo[0], bhi = qhi[0];
#pragma unroll
  for (int qi = 1; qi < KBQ; ++qi) { blo = min(blo, qlo[qi]); bhi = max(bhi, qhi[qi]); }
  const int base = blo & ~3;

  // --- pass 1: per-thread minima per query ---
  for (int i0 = base + 4 * t; i0 < bhi; i0 += 1024) {
    float px[4], py[4], pz[4];
    load4(sxyz, i0, N, px, py, pz);
#pragma unroll
    for (int e = 0; e < 4; ++e) {
      int i = i0 + e;
#pragma unroll
      for (int qi = 0; qi < KBQ; ++qi) {
        float dx = qx[qi] - px[e], dy = qy[qi] - py[e], dz = qz[qi] - pz[e];
        float d2 = fmaf(dx, dx, fmaf(dy, dy, dz * dz));
        bool v = (i >= qlo[qi]) && (i < qhi[qi]);
        qmin[qi] = fminf(qmin[qi], v ? d2 : 3e38f);
      }
    }
  }
#pragma unroll
  for (int qi = 0; qi < KBQ; ++qi) s_min[qi][t] = qmin[qi];
  __syncthreads();

  // --- threshold: 16th smallest of 256 minima; 32-thread group per query ---
  {
    int qi = t >> 5, u = t & 31;
    float v[8];
#pragma unroll
    for (int s = 0; s < 8; ++s) v[s] = s_min[qi][u + 32 * s];
    float thr = 3e38f;
    for (int r = 0; r < KNN; ++r) {
      float lm = fminf(fminf(fminf(v[0], v[1]), fminf(v[2], v[3])),
                       fminf(fminf(v[4], v[5]), fminf(v[6], v[7])));
      float gm = lm;
      gm = fminf(gm, __shfl_xor(gm, 1, 64));
      gm = fminf(gm, __shfl_xor(gm, 2, 64));
      gm = fminf(gm, __shfl_xor(gm, 4, 64));
      gm = fminf(gm, __shfl_xor(gm, 8, 64));
      gm = fminf(gm, __shfl_xor(gm, 16, 64));
      unsigned long long b = __ballot(lm == gm);
      unsigned mask = (unsigned)((b >> (t & 32)) & 0xffffffffull);
      int win = __ffs(mask) - 1;
      if (u == win) {  // knock exactly one instance
        if (v[0] == gm) v[0] = 3e38f; else if (v[1] == gm) v[1] = 3e38f;
        else if (v[2] == gm) v[2] = 3e38f; else if (v[3] == gm) v[3] = 3e38f;
        else if (v[4] == gm) v[4] = 3e38f; else if (v[5] == gm) v[5] = 3e38f;
        else if (v[6] == gm) v[6] = 3e38f; else v[7] = 3e38f;
      }
      thr = gm;
    }
    if (u == 0)
      s_thr[qi] = (s_hi[qi] - s_lo[qi] <= KCAP) ? 3e38f : thr;  // tiny-segment exact
  }
  __syncthreads();

  float qthr[KBQ];
#pragma unroll
  for (int qi = 0; qi < KBQ; ++qi) qthr[qi] = s_thr[qi];

  // --- pass 2: collect survivors ---
  for (int i0 = base + 4 * t; i0 < bhi; i0 += 1024) {
    float px[4], py[4], pz[4];
    load4(sxyz, i0, N, px, py, pz);
#pragma unroll
    for (int e = 0; e < 4; ++e) {
      int i = i0 + e;
#pragma unroll
      for (int qi = 0; qi < KBQ; ++qi) {
        float dx = qx[qi] - px[e], dy = qy[qi] - py[e], dz = qz[qi] - pz[e];
        float d2 = fmaf(dx, dx, fmaf(dy, dy, dz * dz));
        if (i >= qlo[qi] && i < qhi[qi] && d2 <= qthr[qi]) {
          int pos = atomicAdd(&s_cnt[qi], 1);
          if (pos < KCAP)
            s_cand[qi][pos] =
                (((unsigned long long)__float_as_uint(d2)) << 32) | (unsigned)i;
        }
      }
    }
  }
  __syncthreads();

  // --- extraction: 32-thread group per query, 16 exact min rounds ---
  {
    int qi = t >> 5, u = t & 31;
    int M = min(s_cnt[qi], KCAP);
    for (int r = 0; r < KNN; ++r) {
      unsigned long long lm = ~0ull; int ls = -1;
      for (int s = u; s < M; s += 32) {
        unsigned long long vv = s_cand[qi][s];
        if (vv < lm) { lm = vv; ls = s; }
      }
      unsigned long long gm = lm, o;
      o = __shfl_xor(gm, 1, 64); if (o < gm) gm = o;
      o = __shfl_xor(gm, 2, 64); if (o < gm) gm = o;
      o = __shfl_xor(gm, 4, 64); if (o < gm) gm = o;
      o = __shfl_xor(gm, 8, 64); if (o < gm) gm = o;
      o = __shfl_xor(gm, 16, 64); if (o < gm) gm = o;
      unsigned long long b = __ballot(lm == gm);
      unsigned mask = (unsigned)((b >> (t & 32)) & 0xffffffffull);
      int win = __ffs(mask) - 1;
      if (u == win && ls >= 0 && gm != ~0ull) {
        s_cand[qi][ls] = ~0ull;  // group is intra-wave -> in-order LDS, no barrier
        col[(size_t)(qbase + qi) * KNN + r] = (int)(unsigned)(gm & 0xffffffffull);
      }
    }
  }
}

// ---------------------------------------------------------------------------
// Fused per-query kernel — r7 body verbatim (best measured: 153.6us fused,
// 357.9us total). Session constraints established: insensitive to occupancy
// (r3: 21->39% flat), DS-count beyond this point (r7: -40% DS -> -4%), and
// auction folding (r8: +17 fused vs -8 remainder). Keep.
// ---------------------------------------------------------------------------
#define OFF_LEAF 0     // 8 rows x stride 388 (pad 4/row, 16B rows)
#define OFF_EDGE 3104  // 16 x 132 (16B-aligned rows)
#define OFF_B 5216     // union: hidden 16x68 | cls 16x132
#define OFF_EW 7328    // 16 x 12 ; reused as mat 8x17 in EXT=false
#define OFF_FC 7520    // 16 x 20
#define S_TOTAL 7840

template <bool EXT>
__global__ __launch_bounds__(128) void fused_kernel(
    const float* __restrict__ sxyz,
    const int* __restrict__ fidx,
    const float* __restrict__ gcn,
    const float* __restrict__ leaf,
    const float* __restrict__ W1, const float* __restrict__ b1,
    const float* __restrict__ W2, const float* __restrict__ b2,
    const float* __restrict__ Wl, const float* __restrict__ bl,
    const int* __restrict__ col,
    float* __restrict__ matw, float* __restrict__ out) {
  const int q = blockIdx.x;
  const int t = threadIdx.x;
  const int lane = t & 63;
  const int kbase = (t >> 6) * 8;  // wave 0 -> k 0..7, wave 1 -> k 8..15

  __shared__ __align__(16) float S[S_TOTAL];
  __shared__ int s_col[KNN];
  __shared__ float s_rna[24];
  __shared__ float s_rnb[3][KNN];

  // --- stage leaf (12 KB) first: coalesced float4, latency hidden by MLP ---
  {
    const float4* lp = (const float4*)(leaf + (size_t)q * 3072);
#pragma unroll
    for (int r = 0; r < 6; ++r) {
      int v = r * 128 + t;
      float4 f = lp[v];
      int l = v / 96, off = (v % 96) * 4;
      *(float4*)&S[OFF_LEAF + l * 388 + off] = f;
    }
  }
  if (t < KNN) s_col[t] = col[q * KNN + t];
  __syncthreads();

  for (int v = t; v < KNN * 20; v += 128)
    S[OFF_FC + v] = gcn[(size_t)s_col[v / 20] * 148 + 128 + (v % 20)];
  if (t < KNN) {
    int fi = fidx[q];
    float qx = sxyz[3 * fi], qy = sxyz[3 * fi + 1], qz = sxyz[3 * fi + 2];
    int j = s_col[t];
    float jx = sxyz[3 * j], jy = sxyz[3 * j + 1], jz = sxyz[3 * j + 2];
    float dx = qx - jx, dy = qy - jy, dz = qz - jz;
    float dist = sqrtf(dx * dx + dy * dy + dz * dz);
    float* e = &S[OFF_EW + t * 12];
    e[0] = qx; e[1] = qy; e[2] = qz;
    e[3] = jx; e[4] = jy; e[5] = jz;
    e[6] = dx; e[7] = dy; e[8] = dz; e[9] = dist;
  }
  __syncthreads();

  // MLP layer 1 -> hidden (region B, stride 68). EW row as 3x b128 broadcast;
  // components used in ascending i order -> exact.
  for (int r = 0; r < 8; ++r) {
    int o = r * 128 + t;
    int k = o >> 6, jj = o & 63;
    const float* e = &S[OFF_EW + k * 12];
    float4 e0 = *(const float4*)&e[0];
    float4 e1 = *(const float4*)&e[4];
    float4 e2 = *(const float4*)&e[8];
    float acc0 = b1[jj];
    acc0 = fmaf(e0.x, W1[0 * 64 + jj], acc0);
    acc0 = fmaf(e0.y, W1[1 * 64 + jj], acc0);
    acc0 = fmaf(e0.z, W1[2 * 64 + jj], acc0);
    acc0 = fmaf(e0.w, W1[3 * 64 + jj], acc0);
    acc0 = fmaf(e1.x, W1[4 * 64 + jj], acc0);
    acc0 = fmaf(e1.y, W1[5 * 64 + jj], acc0);
    acc0 = fmaf(e1.z, W1[6 * 64 + jj], acc0);
    acc0 = fmaf(e1.w, W1[7 * 64 + jj], acc0);
    acc0 = fmaf(e2.x, W1[8 * 64 + jj], acc0);
    acc0 = fmaf(e2.y, W1[9 * 64 + jj], acc0);
    S[OFF_B + k * 68 + jj] = fmaxf(acc0, 0.0f);
  }
  __syncthreads();

  // MLP layer 2, k-split across waves: wave w -> k=8w..8w+7, h0=lane,
  // h1=lane+64. W2 dword loads coalesced; chain b2[h] + j ascending -> exact.
  {
    float accA[8], accB[8];
#pragma unroll
    for (int k = 0; k < 8; ++k) { accA[k] = b2[lane]; accB[k] = b2[lane + 64]; }
#pragma unroll
    for (int j4 = 0; j4 < 16; ++j4) {
      float4 hv[8];
#pragma unroll
      for (int k = 0; k < 8; ++k)
        hv[k] = *(const float4*)&S[OFF_B + (kbase + k) * 68 + 4 * j4];
#pragma unroll
      for (int jj = 0; jj < 4; ++jj) {
        float wA = W2[(4 * j4 + jj) * 128 + lane];
        float wB = W2[(4 * j4 + jj) * 128 + lane + 64];
#pragma unroll
        for (int k = 0; k < 8; ++k) {
          float hvj = (jj == 0) ? hv[k].x : (jj == 1) ? hv[k].y
                    : (jj == 2) ? hv[k].z : hv[k].w;
          accA[k] = fmaf(hvj, wA, accA[k]);
          accB[k] = fmaf(hvj, wB, accB[k]);
        }
      }
    }
#pragma unroll
    for (int k = 0; k < 8; ++k) {
      S[OFF_EDGE + (kbase + k) * 132 + lane] = accA[k];
      S[OFF_EDGE + (kbase + k) * 132 + lane + 64] = accB[k];
    }
  }
  __syncthreads();  // hidden fully consumed before cls overwrites region B

  // cls GEMV -> region B (stride 132), k-split like MLP2. Wl in 2x20 regs;
  // fc rows as 5x b128 broadcast. Chain: bl[h] + c ascending -> exact.
  {
    float wlA[20], wlB[20];
#pragma unroll
    for (int c = 0; c < 20; ++c) {
      wlA[c] = Wl[c * 128 + lane];
      wlB[c] = Wl[c * 128 + lane + 64];
    }
#pragma unroll
    for (int k = 0; k < 8; ++k) {
      const float* fc = &S[OFF_FC + (kbase + k) * 20];
      float4 f0 = *(const float4*)&fc[0];
      float4 f1 = *(const float4*)&fc[4];
      float4 f2 = *(const float4*)&fc[8];
      float4 f3 = *(const float4*)&fc[12];
      float4 f4 = *(const float4*)&fc[16];
      float aA = bl[lane], aB = bl[lane + 64];
      aA = fmaf(f0.x, wlA[0], aA);  aB = fmaf(f0.x, wlB[0], aB);
      aA = fmaf(f0.y, wlA[1], aA);  aB = fmaf(f0.y, wlB[1], aB);
      aA = fmaf(f0.z, wlA[2], aA);  aB = fmaf(f0.z, wlB[2], aB);
      aA = fmaf(f0.w, wlA[3], aA);  aB = fmaf(f0.w, wlB[3], aB);
      aA = fmaf(f1.x, wlA[4], aA);  aB = fmaf(f1.x, wlB[4], aB);
      aA = fmaf(f1.y, wlA[5], aA);  aB = fmaf(f1.y, wlB[5], aB);
      aA = fmaf(f1.z, wlA[6], aA);  aB = fmaf(f1.z, wlB[6], aB);
      aA = fmaf(f1.w, wlA[7], aA);  aB = fmaf(f1.w, wlB[7], aB);
      aA = fmaf(f2.x, wlA[8], aA);  aB = fmaf(f2.x, wlB[8], aB);
      aA = fmaf(f2.y, wlA[9], aA);  aB = fmaf(f2.y, wlB[9], aB);
      aA = fmaf(f2.z, wlA[10], aA); aB = fmaf(f2.z, wlB[10], aB);
      aA = fmaf(f2.w, wlA[11], aA); aB = fmaf(f2.w, wlB[11], aB);
      aA = fmaf(f3.x, wlA[12], aA); aB = fmaf(f3.x, wlB[12], aB);
      aA = fmaf(f3.y, wlA[13], aA); aB = fmaf(f3.y, wlB[13], aB);
      aA = fmaf(f3.z, wlA[14], aA); aB = fmaf(f3.z, wlB[14], aB);
      aA = fmaf(f3.w, wlA[15], aA); aB = fmaf(f3.w, wlB[15], aB);
      aA = fmaf(f4.x, wlA[16], aA); aB = fmaf(f4.x, wlB[16], aB);
      aA = fmaf(f4.y, wlA[17], aA); aB = fmaf(f4.y, wlB[17], aB);
      aA = fmaf(f4.z, wlA[18], aA); aB = fmaf(f4.z, wlB[18], aB);
      aA = fmaf(f4.w, wlA[19], aA); aB = fmaf(f4.w, wlB[19], aB);
      S[OFF_B + (kbase + k) * 132 + lane] = aA;
      S[OFF_B + (kbase + k) * 132 + lane + 64] = aB;
    }
  }
  __syncthreads();

  // 72 norm jobs. LDS reads as float4 (same component->accumulator mapping).
  if (t < 72) {
    float s0 = 0, s1 = 0, s2 = 0, s3 = 0;
    const float4* p;
    if (t < 24) p = (const float4*)&S[OFF_LEAF + (t / 3) * 388 + (t % 3) * 128];
    else if (t < 40) p = (const float4*)&S[OFF_EDGE + (t - 24) * 132];
    else if (t < 56) p = (const float4*)&S[OFF_B + (t - 40) * 132];
    else p = (const float4*)(gcn + (size_t)s_col[t - 56] * 148);
#pragma unroll 4
    for (int h = 0; h < 32; ++h) {
      float4 v = p[h];
      s0 = fmaf(v.x, v.x, s0); s1 = fmaf(v.y, v.y, s1);
      s2 = fmaf(v.z, v.z, s2); s3 = fmaf(v.w, v.w, s3);
    }
    float rn = 1.0f / fmaxf(sqrtf((s0 + s1) + (s2 + s3)), 1e-8f);
    if (t < 24) s_rna[t] = rn;
    else if (t < 40) s_rnb[0][t - 24] = rn;
    else if (t < 56) s_rnb[1][t - 40] = rn;
    else s_rnb[2][t - 56] = rn;
  }
  __syncthreads();

  // 128 cosine dots -> mat. fma component order unchanged -> exact.
  {
    int l = t >> 4, k = t & 15;
    const float* a0 = &S[OFF_LEAF + l * 388];
    const float* be = &S[OFF_EDGE + k * 132];
    const float* bc = &S[OFF_B + k * 132];
    const float* bf = gcn + (size_t)s_col[k] * 148;
    float d0 = 0, d1 = 0, d2 = 0;
    for (int h = 0; h < 128; h += 4) {
      float4 va0 = *(const float4*)&a0[h];
      float4 va1 = *(const float4*)&a0[128 + h];
      float4 va2 = *(const float4*)&a0[256 + h];
      float4 vbf = *(const float4*)&bf[h];
      float4 ve = *(const float4*)&be[h];
      float4 vc = *(const float4*)&bc[h];
      d0 = fmaf(va0.x, ve.x, d0); d0 = fmaf(va0.y, ve.y, d0);
      d0 = fmaf(va0.z, ve.z, d0); d0 = fmaf(va0.w, ve.w, d0);
      d1 = fmaf(va1.x, vc.x, d1); d1 = fmaf(va1.y, vc.y, d1);
      d1 = fmaf(va1.z, vc.z, d1); d1 = fmaf(va1.w, vc.w, d1);
      d2 = fmaf(va2.x, vbf.x, d2); d2 = fmaf(va2.y, vbf.y, d2);
      d2 = fmaf(va2.z, vbf.z, d2); d2 = fmaf(va2.w, vbf.w, d2);
    }
    float m = (d0 * s_rna[l * 3 + 0] * s_rnb[0][k] +
               d1 * s_rna[l * 3 + 1] * s_rnb[1][k]) * 0.25f +
              d2 * s_rna[l * 3 + 2] * s_rnb[2][k] * 0.5f;
    if (EXT) {
      matw[(size_t)q * 128 + t] = m;
      return;
    }
    S[OFF_EW + l * 17 + k] = m;  // mat 8x17 aliases dead EW region
  }
  __syncthreads();
  if (t >= 64) return;

  // fallback inline auction (workspace too small for mat)
  const float* s_mat = &S[OFF_EW];
  float mrow[KNN];
#pragma unroll
  for (int c = 0; c < KNN; ++c) mrow[c] = s_mat[(t & 7) * 17 + c];
  int ass = -1;
  float cost = 0.f;
  for (int it = 0; it < 1024; ++it) {
    float v1 = -3e38f, v2 = -3e38f; int c1 = 0;
#pragma unroll
    for (int c = 0; c < KNN; ++c) {
      float costc = __shfl(cost, c, 64);
      float v = mrow[c] - costc;
      if (v > v1) { v2 = v1; v1 = v; c1 = c; }
      else if (v > v2) v2 = v;
    }
    int bidc = (t < 8 && ass < 0) ? c1 : -1;
    float bidv = v1 - v2 + 0.125f;
    float high = -3e38f; int hb = -1;
#pragma unroll
    for (int r = 0; r < 8; ++r) {
      int bc = __shfl(bidc, r, 64);
      float bv = __shfl(bidv, r, 64);
      if (bc == t && bv > high) { high = bv; hb = r; }
    }
    if (t < 16 && hb >= 0) cost += high;
    int hb_c = __shfl(hb, bidc < 0 ? 0 : bidc, 64);
    int hb_a = __shfl(hb, ass < 0 ? 0 : ass, 64);
    if (t < 8) {
      if (ass >= 0 && hb_a >= 0) ass = -1;
      if (bidc >= 0 && hb_c == t) ass = bidc;
    }
    if (__ballot((t < 8) ? (ass >= 0) : 1) == ~0ull) break;
  }
  float s = 0.f;
#pragma unroll
  for (int r = 0; r < 8; ++r) {
    int a = __shfl(ass, r, 64);
    if (t == 0) s += s_mat[r * 17 + a];
  }
  if (t == 0) out[q] = s * 0.125f;
}

// ---------------------------------------------------------------------------
// Auction kernel: 16 lanes per query (rows=lanes 0..7, cols=lanes 0..15),
// 4 queries/wave, 16/block. Pure register+shuffle synchronous Jacobi with
// exact reference tie-breaks (strict > scans: lowest col / lowest row).
// ---------------------------------------------------------------------------
__global__ __launch_bounds__(256) void auction_kernel(
    const float* __restrict__ matw, float* __restrict__ out, int Q) {
  const int t = threadIdx.x;
  const int lane = t & 63;
  const int gj = lane & 15;
  const int gb = lane & ~15;  // group base within wave
  const int q = blockIdx.x * 16 + (t >> 6) * 4 + (lane >> 4);
  const bool valid = q < Q;

  float mrow[KNN];
  if (valid && gj < 8) {
    const float4* mp = (const float4*)(matw + (size_t)q * 128 + gj * 16);
    float4 a = mp[0], b = mp[1], c = mp[2], d = mp[3];
    mrow[0] = a.x; mrow[1] = a.y; mrow[2] = a.z; mrow[3] = a.w;
    mrow[4] = b.x; mrow[5] = b.y; mrow[6] = b.z; mrow[7] = b.w;
    mrow[8] = c.x; mrow[9] = c.y; mrow[10] = c.z; mrow[11] = c.w;
    mrow[12] = d.x; mrow[13] = d.y; mrow[14] = d.z; mrow[15] = d.w;
  } else {
#pragma unroll
    for (int c = 0; c < KNN; ++c) mrow[c] = 0.f;
  }
  int ass = (valid && gj < 8) ? -1 : 0;  // cols/invalid lanes report "done"
  float cost = 0.f;

  for (int it = 0; it < 512; ++it) {
    float v1 = -3e38f, v2 = -3e38f; int c1 = 0;
#pragma unroll
    for (int c = 0; c < KNN; ++c) {
      float costc = __shfl(cost, gb + c, 64);
      float v = mrow[c] - costc;
      if (v > v1) { v2 = v1; v1 = v; c1 = c; }
      else if (v > v2) v2 = v;
    }
    int bidc = (valid && gj < 8 && ass < 0) ? c1 : -1;
    float bidv = v1 - v2 + 0.125f;  // eps = 1/L

    float high = -3e38f; int hb = -1;
#pragma unroll
    for (int r = 0; r < 8; ++r) {
      int bc = __shfl(bidc, gb + r, 64);
      float bv = __shfl(bidv, gb + r, 64);
      if (bc == gj && bv > high) { high = bv; hb = r; }
    }
    if (hb >= 0) cost += high;  // lane gj == column gj

    int hb_c = __shfl(hb, gb + (bidc < 0 ? 0 : bidc), 64);
    int hb_a = __shfl(hb, gb + (ass < 0 ? 0 : ass), 64);
    if (valid && gj < 8) {
      if (ass >= 0 && hb_a >= 0) ass = -1;     // kicked
      if (bidc >= 0 && hb_c == gj) ass = bidc; // won
    }
    if (__ballot(ass >= 0) == ~0ull) break;
  }

  float val = 0.f;
  if (valid && gj < 8) {
#pragma unroll
    for (int c = 0; c < KNN; ++c) val = (ass == c) ? mrow[c] : val;
  }
  val += __shfl_xor(val, 1, 64);
  val += __shfl_xor(val, 2, 64);
  val += __shfl_xor(val, 4, 64);
  if (valid && gj == 0) out[q] = val * 0.125f;
}

// ---------------------------------------------------------------------------
extern "C" void kernel_launch(void* const* d_in, const int* in_sizes, int n_in,
                              void* d_out, int out_size, void* d_ws, size_t ws_size,
                              hipStream_t stream) {
  const float* sxyz = (const float*)d_in[0];
  const int* bidx = (const int*)d_in[1];
  const int* fidx = (const int*)d_in[2];
  const float* gcn = (const float*)d_in[3];
  const float* leaf = (const float*)d_in[4];
  const float* W1 = (const float*)d_in[5];
  const float* b1 = (const float*)d_in[6];
  const float* W2 = (const float*)d_in[7];
  const float* b2 = (const float*)d_in[8];
  const float* Wl = (const float*)d_in[9];
  const float* bl = (const float*)d_in[10];
  float* out = (float*)d_out;

  const int N = in_sizes[0] / 3;
  const int Q = in_sizes[2];

  char* ws = (char*)d_ws;
  int* col = (int*)ws;
  float* matw = (float*)(ws + (size_t)Q * KNN * 4);
  const size_t need = (size_t)Q * KNN * 4 + (size_t)Q * 128 * 4;

  knn_kernel<<<(Q + KBQ - 1) / KBQ, 256, 0, stream>>>(sxyz, bidx, fidx, col, N, Q);
  if (ws_size >= need) {
    fused_kernel<true><<<Q, 128, 0, stream>>>(sxyz, fidx, gcn, leaf, W1, b1, W2,
                                              b2, Wl, bl, col, matw, out);
    auction_kernel<<<(Q + 15) / 16, 256, 0, stream>>>(matw, out, Q);
  } else {
    fused_kernel<false><<<Q, 128, 0, stream>>>(sxyz, fidx, gcn, leaf, W1, b1, W2,
                                               b2, Wl, bl, col, nullptr, out);
  }
}